// Round 7
// baseline (278.521 us; speedup 1.0000x reference)
//
#include <hip/hip_runtime.h>
#include <hip/hip_bf16.h>
#include <math.h>

#define N_NODES 50000
#define N_EDGES 600000
#define DIM 128
#define KGAM 8
#define EPSV 1e-9f

// CSR chunk scan: 25 chunks of 2048 nodes
#define CHUNK_SHIFT 11
#define NCHUNKS 25

// SpMM D-slicing: 4 passes x 32 dims; 3125 node-blocks of 16 nodes
#define NPASS 4
#define NBLK 3125

typedef __attribute__((ext_vector_type(8))) short short8;
typedef __attribute__((ext_vector_type(4))) float float4v;

__device__ __forceinline__ float bf2f(short s) {
    unsigned int u = ((unsigned int)(unsigned short)s) << 16;
    return __builtin_bit_cast(float, u);
}
__device__ __forceinline__ short f2bf(float f) {
    return (short)__builtin_bit_cast(unsigned short, __float2bfloat16(f));
}
__device__ __forceinline__ unsigned int pack2(float a, float b) {
    return (unsigned int)(unsigned short)f2bf(a) | ((unsigned int)(unsigned short)f2bf(b) << 16);
}
__device__ __forceinline__ float sigm(float x) { return 1.f / (1.f + __expf(-x)); }
__device__ __forceinline__ float ulo(unsigned int u) { return __builtin_bit_cast(float, u << 16); }
__device__ __forceinline__ float uhi(unsigned int u) { return __builtin_bit_cast(float, u & 0xffff0000u); }

// ---------------- fused prep: fb convert + Wb convert + coeffs (blocks 0..3173)
//                  CONCURRENT edge-degree atomics (blocks 3174..5517) --------------
// deg pre-zeroed by hipMemsetAsync before this kernel.
__global__ void k_prep_deg(const float4* __restrict__ feat4,
                           const float* __restrict__ W0, const float* __restrict__ W1,
                           const float* __restrict__ W2,
                           const float* __restrict__ gl, const float* __restrict__ gh,
                           const float* __restrict__ gm,
                           const int* __restrict__ dst,
                           uint4* __restrict__ fb4, unsigned int* __restrict__ Wb,
                           float* __restrict__ coeffs, int* __restrict__ deg) {
    int b = blockIdx.x, tid = threadIdx.x;
    if (b < 3125) {
        int idx = b * 256 + tid;                     // group of 8 floats; 800000 exact
        float4 v0 = feat4[idx * 2];
        float4 v1 = feat4[idx * 2 + 1];
        uint4 o;
        o.x = pack2(v0.x, v0.y); o.y = pack2(v0.z, v0.w);
        o.z = pack2(v1.x, v1.y); o.w = pack2(v1.z, v1.w);
        fb4[idx] = o;
    } else if (b < 3173) {
        int j = (b - 3125) * 256 + tid;              // [0, 12288)
        int g = j >> 12;
        int i = (j & 4095) * 4;
        const float* Ws = (g == 0) ? W0 : (g == 1) ? W1 : W2;
        float4 v = *(const float4*)(Ws + i);
        uint2 o; o.x = pack2(v.x, v.y); o.y = pack2(v.z, v.w);
        *(uint2*)(Wb + (g * DIM * DIM + i) / 2) = o;
    } else if (b == 3173) {
        if (tid == 0) {
            float a0 = 0, b0 = 0, a1 = 0, b1 = 0, sg = 0, m2 = 0;
            for (int k = 0; k < KGAM; ++k) {
                float al = EPSV + (float)k * (1.f - 2.f * EPSV) / (KGAM - 1);
                float md = EPSV + (float)k * (1.f - EPSV) / (KGAM - 1);
                float l = fmaxf(gl[k], 0.f), h = fmaxf(gh[k], 0.f), m = fmaxf(gm[k], 0.f);
                a0 += al * l;  b0 += (1.f - al) * l;
                a1 += -al * h; b1 += (1.f - al) * h;
                sg += m;       m2 += md * m;
            }
            coeffs[0] = a0; coeffs[1] = b0; coeffs[2] = a1;
            coeffs[3] = b1; coeffs[4] = sg; coeffs[5] = -m2;
        }
    } else {
        int e = (b - 3174) * 256 + tid;
        if (e < N_EDGES) atomicAdd(&deg[dst[e]], 1);
    }
}

// ---------------- fused scan: per-chunk exclusive scan + norm; last block scans
//                  the 25 chunk sums (atomic-ticket pattern, no spin) -------------
__global__ __launch_bounds__(512) void k_scan(const int* __restrict__ deg,
                                              int* __restrict__ rowstart,
                                              int* __restrict__ bsums,
                                              float* __restrict__ norm,
                                              int* __restrict__ done) {
    __shared__ int s[512];
    __shared__ int lastf;
    __shared__ int bs[NCHUNKS];
    int tid = threadIdx.x;
    int i0 = blockIdx.x * 2048 + tid * 4;
    int v[4]; int sum = 0;
#pragma unroll
    for (int c = 0; c < 4; ++c) {
        int i = i0 + c;
        int d = (i < N_NODES) ? deg[i] : 0;
        v[c] = d; sum += d;
    }
    s[tid] = sum; __syncthreads();
#pragma unroll
    for (int off = 1; off < 512; off <<= 1) {
        int t = (tid >= off) ? s[tid - off] : 0;
        __syncthreads();
        s[tid] += t;
        __syncthreads();
    }
    if (tid == 511) bsums[blockIdx.x] = s[511];
    int run = s[tid] - sum;
#pragma unroll
    for (int c = 0; c < 4; ++c) {
        int i = i0 + c;
        if (i < N_NODES) {
            rowstart[i] = run;                       // chunk-local exclusive prefix
            norm[i] = rsqrtf((float)(v[c] < 1 ? 1 : v[c]));
        }
        run += v[c];
    }
    // last-arriving block turns bsums into an exclusive prefix of chunk sums
    __threadfence();
    __syncthreads();
    if (tid == 0) {
        int old = atomicAdd(done, 1);
        lastf = (old == (int)gridDim.x - 1) ? 1 : 0;
    }
    __syncthreads();
    if (lastf) {
        __threadfence();
        if (tid < NCHUNKS) bs[tid] = bsums[tid];
        __syncthreads();
        if (tid == 0) {
            int run2 = 0;
            for (int i = 0; i < NCHUNKS; ++i) { int t = bs[i]; bs[i] = run2; run2 += t; }
        }
        __syncthreads();
        if (tid < NCHUNKS) bsums[tid] = bs[tid];
    }
}

// ---------------- CSR fill: packed (src, norm[src]) records ----------------
__global__ void k_fill(const int* __restrict__ src, const int* __restrict__ dst,
                       const int* __restrict__ rowstart, const int* __restrict__ bsums,
                       int* __restrict__ cnt, const float* __restrict__ norm,
                       uint2* __restrict__ er) {
    int e = blockIdx.x * blockDim.x + threadIdx.x;
    if (e < N_EDGES) {
        int d = dst[e];
        int slot = rowstart[d] + bsums[d >> CHUNK_SHIFT] + atomicAdd(&cnt[d], 1);
        int u = src[e];
        uint2 rec;
        rec.x = (unsigned int)u;
        rec.y = __builtin_bit_cast(unsigned int, norm[u]);
        er[slot] = rec;
    }
}

// ---------------- SpMM, D-sliced pass-major: 4 passes x 32 dims ---------------
// pass = bid / NBLK so dispatch order keeps concurrent blocks in the same pass:
// per-pass gather working set = 50000 * 64B = 3.2MB < 4MiB per-XCD L2 (no thrash).
// Per-dim edge accumulation order identical to unsliced version -> bit-identical.
__global__ __launch_bounds__(256, 6) void k_spmm_slice(
    const unsigned int* __restrict__ in, const float* __restrict__ norm,
    const int* __restrict__ rowstart, const int* __restrict__ bsums,
    const uint2* __restrict__ er, unsigned int* __restrict__ out) {
    int bid = blockIdx.x;
    int pass = bid / NBLK;                 // 0..3
    int nb = bid - pass * NBLK;
    int grp = threadIdx.x >> 4;
    int l = threadIdx.x & 15;
    int node = nb * 16 + grp;              // 3125*16 = 50000 exact
    int beg = rowstart[node] + bsums[node >> CHUNK_SHIFT];
    int end = (node == N_NODES - 1)
                  ? N_EDGES
                  : rowstart[node + 1] + bsums[(node + 1) >> CHUNK_SHIFT];
    const unsigned int* ip = in + pass * 16 + l;   // lane's 2-dim column in slice
    float ax = 0.f, ay = 0.f;
    int t = beg;
    for (; t + 7 < end; t += 8) {
        uint2 e0 = er[t],     e1 = er[t + 1], e2 = er[t + 2], e3 = er[t + 3];
        uint2 e4 = er[t + 4], e5 = er[t + 5], e6 = er[t + 6], e7 = er[t + 7];
        unsigned int r0 = ip[e0.x * 64u];
        unsigned int r1 = ip[e1.x * 64u];
        unsigned int r2 = ip[e2.x * 64u];
        unsigned int r3 = ip[e3.x * 64u];
        unsigned int r4 = ip[e4.x * 64u];
        unsigned int r5 = ip[e5.x * 64u];
        unsigned int r6 = ip[e6.x * 64u];
        unsigned int r7 = ip[e7.x * 64u];
        float n0 = __builtin_bit_cast(float, e0.y), n1 = __builtin_bit_cast(float, e1.y);
        float n2 = __builtin_bit_cast(float, e2.y), n3 = __builtin_bit_cast(float, e3.y);
        float n4 = __builtin_bit_cast(float, e4.y), n5 = __builtin_bit_cast(float, e5.y);
        float n6 = __builtin_bit_cast(float, e6.y), n7 = __builtin_bit_cast(float, e7.y);
        ax = fmaf(n0, ulo(r0), ax); ay = fmaf(n0, uhi(r0), ay);
        ax = fmaf(n1, ulo(r1), ax); ay = fmaf(n1, uhi(r1), ay);
        ax = fmaf(n2, ulo(r2), ax); ay = fmaf(n2, uhi(r2), ay);
        ax = fmaf(n3, ulo(r3), ax); ay = fmaf(n3, uhi(r3), ay);
        ax = fmaf(n4, ulo(r4), ax); ay = fmaf(n4, uhi(r4), ay);
        ax = fmaf(n5, ulo(r5), ax); ay = fmaf(n5, uhi(r5), ay);
        ax = fmaf(n6, ulo(r6), ax); ay = fmaf(n6, uhi(r6), ay);
        ax = fmaf(n7, ulo(r7), ax); ay = fmaf(n7, uhi(r7), ay);
    }
    if (t + 3 < end) {
        uint2 e0 = er[t], e1 = er[t + 1], e2 = er[t + 2], e3 = er[t + 3];
        unsigned int r0 = ip[e0.x * 64u];
        unsigned int r1 = ip[e1.x * 64u];
        unsigned int r2 = ip[e2.x * 64u];
        unsigned int r3 = ip[e3.x * 64u];
        float n0 = __builtin_bit_cast(float, e0.y), n1 = __builtin_bit_cast(float, e1.y);
        float n2 = __builtin_bit_cast(float, e2.y), n3 = __builtin_bit_cast(float, e3.y);
        ax = fmaf(n0, ulo(r0), ax); ay = fmaf(n0, uhi(r0), ay);
        ax = fmaf(n1, ulo(r1), ax); ay = fmaf(n1, uhi(r1), ay);
        ax = fmaf(n2, ulo(r2), ax); ay = fmaf(n2, uhi(r2), ay);
        ax = fmaf(n3, ulo(r3), ax); ay = fmaf(n3, uhi(r3), ay);
        t += 4;
    }
    for (; t < end; ++t) {
        uint2 e = er[t];
        unsigned int r = ip[e.x * 64u];
        float nu = __builtin_bit_cast(float, e.y);
        ax = fmaf(nu, ulo(r), ax); ay = fmaf(nu, uhi(r), ay);
    }
    float nv = norm[node];
    out[(unsigned)node * 64u + pass * 16u + l] = pack2(ax * nv, ay * nv);
}

// ---------------- fused tri-GEMM + gating (bf16 inputs, 8 waves, ct-split) --------
// A: lane holds A[m=lane&15][k=quad*8+j]; B: lane holds W[n=lane&15][k=quad*8+j];
// C/D: col=lane&15, row=quad*4+reg  (verified layout)
// RT=32: LDS 26112B, ~46% occupancy measured.
#define RT 32
#define TSTR 136

__global__ __launch_bounds__(512, 4) void k_gemm_fused(
    const short* __restrict__ hB, const short* __restrict__ fB,
    const short* __restrict__ h1B, const short* __restrict__ Wb,
    const float* __restrict__ coeffs, const float* __restrict__ bias,
    const float* __restrict__ snorm, float* __restrict__ out) {
    __shared__ short Ts[3][RT * TSTR];

    const float c0 = coeffs[0], c1 = coeffs[1], c2 = coeffs[2];
    const float c3 = coeffs[3], c4 = coeffs[4], c5 = coeffs[5];
    const int r0 = blockIdx.x * RT;
    const int tid = threadIdx.x;

    // stage: blend bf16 h/f/h1 -> bf16 T0,T1,T2 tiles (512 threads = 32 rows x 16 cg)
    {
        int r = tid >> 4;
        int cg = (tid & 15) * 8;
        int row = r0 + r;
        int la = r * TSTR + cg;
        short8 hv = {0,0,0,0,0,0,0,0}, fv = {0,0,0,0,0,0,0,0}, h1v = {0,0,0,0,0,0,0,0};
        if (row < N_NODES) {
            size_t base = (size_t)row * DIM + cg;
            hv  = *(const short8*)(hB + base);
            fv  = *(const short8*)(fB + base);
            h1v = *(const short8*)(h1B + base);
        }
        short8 t0, t1, t2;
#pragma unroll
        for (int j = 0; j < 8; ++j) {
            float hf = bf2f(hv[j]), ff = bf2f(fv[j]), h1f = bf2f(h1v[j]);
            t0[j] = f2bf(c0 * hf + c1 * ff);
            t1[j] = f2bf(c2 * hf + c3 * ff);
            t2[j] = f2bf(c4 * h1f + c5 * ff);
        }
        *(short8*)&Ts[0][la] = t0;
        *(short8*)&Ts[1][la] = t1;
        *(short8*)&Ts[2][la] = t2;
    }
    __syncthreads();

    const int lane = tid & 63;
    const int ct = tid >> 6;        // wave owns one 16-col tile
    const int m = lane & 15;
    const int quad = lane >> 4;

    float4v acc[3][2];
    const float4v zero = {0.f, 0.f, 0.f, 0.f};
#pragma unroll
    for (int g = 0; g < 3; ++g)
#pragma unroll
        for (int rt = 0; rt < 2; ++rt) acc[g][rt] = zero;

    const short* wbase = Wb + (ct * 16 + m) * DIM + quad * 8;
#pragma unroll
    for (int ks = 0; ks < 4; ++ks) {
        const short* wp = wbase + ks * 32;
        short8 b0 = *(const short8*)(wp);
        short8 b1 = *(const short8*)(wp + DIM * DIM);
        short8 b2 = *(const short8*)(wp + 2 * DIM * DIM);
#pragma unroll
        for (int rt = 0; rt < 2; ++rt) {
            int aoff = (rt * 16 + m) * TSTR + ks * 32 + quad * 8;
            short8 a0 = *(const short8*)&Ts[0][aoff];
            short8 a1 = *(const short8*)&Ts[1][aoff];
            short8 a2 = *(const short8*)&Ts[2][aoff];
            acc[0][rt] = __builtin_amdgcn_mfma_f32_16x16x32_bf16(a0, b0, acc[0][rt], 0, 0, 0);
            acc[1][rt] = __builtin_amdgcn_mfma_f32_16x16x32_bf16(a1, b1, acc[1][rt], 0, 0, 0);
            acc[2][rt] = __builtin_amdgcn_mfma_f32_16x16x32_bf16(a2, b2, acc[2][rt], 0, 0, 0);
        }
    }

    // epilogue: sequential mutual gating + bias + graph-norm + relu
    const int col = ct * 16 + m;
    const float bc = bias[col];
#pragma unroll
    for (int rt = 0; rt < 2; ++rt) {
#pragma unroll
        for (int r = 0; r < 4; ++r) {
            int row = r0 + rt * 16 + quad * 4 + r;
            if (row < N_NODES) {
                float sn = snorm[row];
                float o0 = acc[0][rt][r], o1 = acc[1][rt][r], o2 = acc[2][rt][r];
                float g0 = o0 * sigm(o1 + o2);
                float g1 = o1 * sigm(g0 + o2);
                float g2 = o2 * sigm(g0 + g1);
                float vv = (g0 + g1 + g2 + bc) * sn;
                __builtin_nontemporal_store(fmaxf(vv, 0.f), &out[(size_t)row * DIM + col]);
            }
        }
    }
}

extern "C" void kernel_launch(void* const* d_in, const int* in_sizes, int n_in,
                              void* d_out, int out_size, void* d_ws, size_t ws_size,
                              hipStream_t stream) {
    const float* feature = (const float*)d_in[0];
    const float* snorm   = (const float*)d_in[1];
    const int*   src     = (const int*)d_in[2];
    const int*   dst     = (const int*)d_in[3];
    const float* W_low   = (const float*)d_in[4];
    const float* W_high  = (const float*)d_in[5];
    const float* W_mid   = (const float*)d_in[6];
    const float* gl      = (const float*)d_in[7];
    const float* gh      = (const float*)d_in[8];
    const float* gm      = (const float*)d_in[9];
    const float* bias    = (const float*)d_in[10];
    float* out = (float*)d_out;

    char* w = (char*)d_ws;
    auto alloc = [&](size_t bytes) {
        char* p = w;
        w += (bytes + 255) & ~(size_t)255;
        return p;
    };
    // deg, cnt, done contiguous -> single memset zeroes all three
    int* deg      = (int*)alloc((size_t)N_NODES * 4);
    int* cnt      = (int*)alloc((size_t)N_NODES * 4);
    int* done     = (int*)alloc(256);
    size_t zero_bytes = (size_t)((char*)done - (char*)deg) + 256;
    float* norm   = (float*)alloc((size_t)N_NODES * 4);
    int* rowstart = (int*)alloc((size_t)(N_NODES + 1) * 4);
    int* bsums    = (int*)alloc(64 * 4);
    uint2* er     = (uint2*)alloc((size_t)N_EDGES * 8);
    float* coeffs = (float*)alloc(64 * 4);
    short* Wb     = (short*)alloc((size_t)3 * DIM * DIM * 2);
    short* fb     = (short*)alloc((size_t)N_NODES * DIM * 2);
    short* h      = (short*)alloc((size_t)N_NODES * DIM * 2);
    short* h1     = (short*)alloc((size_t)N_NODES * DIM * 2);

    // 0: zero deg + cnt + done
    hipMemsetAsync(deg, 0, zero_bytes, stream);
    // 1: fb/Wb/coeffs convert CONCURRENT with degree atomics (disjoint block roles)
    k_prep_deg<<<3174 + 2344, 256, 0, stream>>>(
        (const float4*)feature, W_low, W_high, W_mid, gl, gh, gm, dst,
        (uint4*)fb, (unsigned int*)Wb, coeffs, deg);
    // 2: chunk scan + norm; last block scans chunk sums
    k_scan<<<NCHUNKS, 512, 0, stream>>>(deg, rowstart, bsums, norm, done);
    // 3: CSR fill with packed (src, norm[src]) records
    k_fill<<<(N_EDGES + 255) / 256, 256, 0, stream>>>(src, dst, rowstart, bsums,
                                                      cnt, norm, er);
    // 4,5: two SpMM hops, D-sliced pass-major for per-XCD L2 residency
    k_spmm_slice<<<NPASS * NBLK, 256, 0, stream>>>(
        (const unsigned int*)fb, norm, rowstart, bsums, er, (unsigned int*)h);
    k_spmm_slice<<<NPASS * NBLK, 256, 0, stream>>>(
        (const unsigned int*)h, norm, rowstart, bsums, er, (unsigned int*)h1);
    // 6: fused tri-GEMM + gating
    k_gemm_fused<<<(N_NODES + RT - 1) / RT, 512, 0, stream>>>(
        h, fb, h1, Wb, coeffs, bias, snorm, out);
}

// Round 9
// 251.513 us; speedup vs baseline: 1.1074x; 1.1074x over previous
//
#include <hip/hip_runtime.h>
#include <hip/hip_bf16.h>
#include <math.h>

#define N_NODES 50000
#define N_EDGES 600000
#define DIM 128
#define KGAM 8
#define EPSV 1e-9f

// CSR chunk scan: 25 chunks of 2048 nodes
#define CHUNK_SHIFT 11
#define NCHUNKS 25

typedef __attribute__((ext_vector_type(8))) short short8;
typedef __attribute__((ext_vector_type(4))) float float4v;

__device__ __forceinline__ float bf2f(short s) {
    unsigned int u = ((unsigned int)(unsigned short)s) << 16;
    return __builtin_bit_cast(float, u);
}
__device__ __forceinline__ short f2bf(float f) {
    return (short)__builtin_bit_cast(unsigned short, __float2bfloat16(f));
}
__device__ __forceinline__ unsigned int pack2(float a, float b) {
    return (unsigned int)(unsigned short)f2bf(a) | ((unsigned int)(unsigned short)f2bf(b) << 16);
}
__device__ __forceinline__ float sigm(float x) { return 1.f / (1.f + __expf(-x)); }
__device__ __forceinline__ float ulo(unsigned int u) { return __builtin_bit_cast(float, u << 16); }
__device__ __forceinline__ float uhi(unsigned int u) { return __builtin_bit_cast(float, u & 0xffff0000u); }

__device__ __forceinline__ void acc8(float4v& a0, float4v& a1, uint4 r, float nu) {
    a0.x = fmaf(nu, ulo(r.x), a0.x); a0.y = fmaf(nu, uhi(r.x), a0.y);
    a0.z = fmaf(nu, ulo(r.y), a0.z); a0.w = fmaf(nu, uhi(r.y), a0.w);
    a1.x = fmaf(nu, ulo(r.z), a1.x); a1.y = fmaf(nu, uhi(r.z), a1.y);
    a1.z = fmaf(nu, ulo(r.w), a1.z); a1.w = fmaf(nu, uhi(r.w), a1.w);
}

// NT load for the streaming edge-record array (bypass L2 so gather rows stay
// resident). Loaded as a scalar u64 (guaranteed-supported NT type), split to pair.
struct EdgeRec { unsigned int x; unsigned int y; };
__device__ __forceinline__ EdgeRec ldnt2(const uint2* p) {
    unsigned long long v =
        __builtin_nontemporal_load((const unsigned long long*)p);
    EdgeRec r;
    r.x = (unsigned int)v;
    r.y = (unsigned int)(v >> 32);
    return r;
}

// ---------------- fused prep: fb convert + Wb convert + coeffs (blocks 0..3173)
//                  CONCURRENT edge-degree atomics (blocks 3174..5517) --------------
// deg pre-zeroed by hipMemsetAsync before this kernel.
__global__ void k_prep_deg(const float4* __restrict__ feat4,
                           const float* __restrict__ W0, const float* __restrict__ W1,
                           const float* __restrict__ W2,
                           const float* __restrict__ gl, const float* __restrict__ gh,
                           const float* __restrict__ gm,
                           const int* __restrict__ dst,
                           uint4* __restrict__ fb4, unsigned int* __restrict__ Wb,
                           float* __restrict__ coeffs, int* __restrict__ deg) {
    int b = blockIdx.x, tid = threadIdx.x;
    if (b < 3125) {
        int idx = b * 256 + tid;                     // group of 8 floats; 800000 exact
        float4 v0 = feat4[idx * 2];
        float4 v1 = feat4[idx * 2 + 1];
        uint4 o;
        o.x = pack2(v0.x, v0.y); o.y = pack2(v0.z, v0.w);
        o.z = pack2(v1.x, v1.y); o.w = pack2(v1.z, v1.w);
        fb4[idx] = o;
    } else if (b < 3173) {
        int j = (b - 3125) * 256 + tid;              // [0, 12288)
        int g = j >> 12;
        int i = (j & 4095) * 4;
        const float* Ws = (g == 0) ? W0 : (g == 1) ? W1 : W2;
        float4 v = *(const float4*)(Ws + i);
        uint2 o; o.x = pack2(v.x, v.y); o.y = pack2(v.z, v.w);
        *(uint2*)(Wb + (g * DIM * DIM + i) / 2) = o;
    } else if (b == 3173) {
        if (tid == 0) {
            float a0 = 0, b0 = 0, a1 = 0, b1 = 0, sg = 0, m2 = 0;
            for (int k = 0; k < KGAM; ++k) {
                float al = EPSV + (float)k * (1.f - 2.f * EPSV) / (KGAM - 1);
                float md = EPSV + (float)k * (1.f - EPSV) / (KGAM - 1);
                float l = fmaxf(gl[k], 0.f), h = fmaxf(gh[k], 0.f), m = fmaxf(gm[k], 0.f);
                a0 += al * l;  b0 += (1.f - al) * l;
                a1 += -al * h; b1 += (1.f - al) * h;
                sg += m;       m2 += md * m;
            }
            coeffs[0] = a0; coeffs[1] = b0; coeffs[2] = a1;
            coeffs[3] = b1; coeffs[4] = sg; coeffs[5] = -m2;
        }
    } else {
        int e = (b - 3174) * 256 + tid;
        if (e < N_EDGES) atomicAdd(&deg[dst[e]], 1);
    }
}

// ---------------- fused scan: per-chunk exclusive scan + norm; last block scans
//                  the 25 chunk sums (atomic-ticket pattern, no spin) -------------
__global__ __launch_bounds__(512) void k_scan(const int* __restrict__ deg,
                                              int* __restrict__ rowstart,
                                              int* __restrict__ bsums,
                                              float* __restrict__ norm,
                                              int* __restrict__ done) {
    __shared__ int s[512];
    __shared__ int lastf;
    __shared__ int bs[NCHUNKS];
    int tid = threadIdx.x;
    int i0 = blockIdx.x * 2048 + tid * 4;
    int v[4]; int sum = 0;
#pragma unroll
    for (int c = 0; c < 4; ++c) {
        int i = i0 + c;
        int d = (i < N_NODES) ? deg[i] : 0;
        v[c] = d; sum += d;
    }
    s[tid] = sum; __syncthreads();
#pragma unroll
    for (int off = 1; off < 512; off <<= 1) {
        int t = (tid >= off) ? s[tid - off] : 0;
        __syncthreads();
        s[tid] += t;
        __syncthreads();
    }
    if (tid == 511) bsums[blockIdx.x] = s[511];
    int run = s[tid] - sum;
#pragma unroll
    for (int c = 0; c < 4; ++c) {
        int i = i0 + c;
        if (i < N_NODES) {
            rowstart[i] = run;                       // chunk-local exclusive prefix
            norm[i] = rsqrtf((float)(v[c] < 1 ? 1 : v[c]));
        }
        run += v[c];
    }
    // last-arriving block turns bsums into an exclusive prefix of chunk sums
    __threadfence();
    __syncthreads();
    if (tid == 0) {
        int old = atomicAdd(done, 1);
        lastf = (old == (int)gridDim.x - 1) ? 1 : 0;
    }
    __syncthreads();
    if (lastf) {
        __threadfence();
        if (tid < NCHUNKS) bs[tid] = bsums[tid];
        __syncthreads();
        if (tid == 0) {
            int run2 = 0;
            for (int i = 0; i < NCHUNKS; ++i) { int t = bs[i]; bs[i] = run2; run2 += t; }
        }
        __syncthreads();
        if (tid < NCHUNKS) bsums[tid] = bs[tid];
    }
}

// ---------------- CSR fill: packed (src, norm[src]) records ----------------
__global__ void k_fill(const int* __restrict__ src, const int* __restrict__ dst,
                       const int* __restrict__ rowstart, const int* __restrict__ bsums,
                       int* __restrict__ cnt, const float* __restrict__ norm,
                       uint2* __restrict__ er) {
    int e = blockIdx.x * blockDim.x + threadIdx.x;
    if (e < N_EDGES) {
        int d = dst[e];
        int slot = rowstart[d] + bsums[d >> CHUNK_SHIFT] + atomicAdd(&cnt[d], 1);
        int u = src[e];
        unsigned long long rec = (unsigned long long)(unsigned int)u |
            ((unsigned long long)__builtin_bit_cast(unsigned int, norm[u]) << 32);
        __builtin_nontemporal_store(rec, (unsigned long long*)&er[slot]);
    }
}

// ---------------- SpMM hop 1: 16 lanes/node, unroll-8, NT edge stream -------------
// out[v] = bf16(norm[v] * sum_u norm[u]*in[u])
__global__ __launch_bounds__(256, 6) void k_spmm(
    const uint4* __restrict__ in, const float* __restrict__ norm,
    const int* __restrict__ rowstart, const int* __restrict__ bsums,
    const uint2* __restrict__ er, uint4* __restrict__ out) {
    int node = blockIdx.x * 16 + (threadIdx.x >> 4);
    if (node >= N_NODES) return;
    int gl = threadIdx.x & 15;
    int beg = rowstart[node] + bsums[node >> CHUNK_SHIFT];
    int end = (node == N_NODES - 1)
                  ? N_EDGES
                  : rowstart[node + 1] + bsums[(node + 1) >> CHUNK_SHIFT];
    float4v a0 = {0.f, 0.f, 0.f, 0.f};
    float4v a1 = {0.f, 0.f, 0.f, 0.f};
    int t = beg;
    for (; t + 7 < end; t += 8) {
        EdgeRec e0 = ldnt2(er + t),     e1 = ldnt2(er + t + 1);
        EdgeRec e2 = ldnt2(er + t + 2), e3 = ldnt2(er + t + 3);
        EdgeRec e4 = ldnt2(er + t + 4), e5 = ldnt2(er + t + 5);
        EdgeRec e6 = ldnt2(er + t + 6), e7 = ldnt2(er + t + 7);
        uint4 r0 = in[e0.x * 16u + gl];
        uint4 r1 = in[e1.x * 16u + gl];
        uint4 r2 = in[e2.x * 16u + gl];
        uint4 r3 = in[e3.x * 16u + gl];
        uint4 r4 = in[e4.x * 16u + gl];
        uint4 r5 = in[e5.x * 16u + gl];
        uint4 r6 = in[e6.x * 16u + gl];
        uint4 r7 = in[e7.x * 16u + gl];
        acc8(a0, a1, r0, __builtin_bit_cast(float, e0.y));
        acc8(a0, a1, r1, __builtin_bit_cast(float, e1.y));
        acc8(a0, a1, r2, __builtin_bit_cast(float, e2.y));
        acc8(a0, a1, r3, __builtin_bit_cast(float, e3.y));
        acc8(a0, a1, r4, __builtin_bit_cast(float, e4.y));
        acc8(a0, a1, r5, __builtin_bit_cast(float, e5.y));
        acc8(a0, a1, r6, __builtin_bit_cast(float, e6.y));
        acc8(a0, a1, r7, __builtin_bit_cast(float, e7.y));
    }
    if (t + 3 < end) {
        EdgeRec e0 = ldnt2(er + t),     e1 = ldnt2(er + t + 1);
        EdgeRec e2 = ldnt2(er + t + 2), e3 = ldnt2(er + t + 3);
        uint4 r0 = in[e0.x * 16u + gl];
        uint4 r1 = in[e1.x * 16u + gl];
        uint4 r2 = in[e2.x * 16u + gl];
        uint4 r3 = in[e3.x * 16u + gl];
        acc8(a0, a1, r0, __builtin_bit_cast(float, e0.y));
        acc8(a0, a1, r1, __builtin_bit_cast(float, e1.y));
        acc8(a0, a1, r2, __builtin_bit_cast(float, e2.y));
        acc8(a0, a1, r3, __builtin_bit_cast(float, e3.y));
        t += 4;
    }
    for (; t < end; ++t) {
        EdgeRec e = ldnt2(er + t);
        uint4 r = in[e.x * 16u + gl];
        acc8(a0, a1, r, __builtin_bit_cast(float, e.y));
    }
    float nv = norm[node];
    uint4 o;
    o.x = pack2(a0.x * nv, a0.y * nv); o.y = pack2(a0.z * nv, a0.w * nv);
    o.z = pack2(a1.x * nv, a1.y * nv); o.w = pack2(a1.z * nv, a1.w * nv);
    out[node * 16u + gl] = o;
}

// ---------------- fused: SpMM hop 2 (h -> h1, LDS-resident) + tri-GEMM + gating ---
// A: lane holds A[m=lane&15][k=quad*8+j]; B: lane holds W[n=lane&15][k=quad*8+j];
// C/D: col=lane&15, row=quad*4+reg  (verified layout)
// RT=32: LDS 26112B -> ~46% occupancy measured (R6).
#define RT 32
#define TSTR 136

__global__ __launch_bounds__(512, 4) void k_gemm_fused(
    const uint4* __restrict__ h4, const short* __restrict__ fB,
    const short* __restrict__ Wb,
    const int* __restrict__ rowstart, const int* __restrict__ bsums,
    const float* __restrict__ norm, const uint2* __restrict__ er,
    const float* __restrict__ coeffs, const float* __restrict__ bias,
    const float* __restrict__ snorm, float* __restrict__ out) {
    __shared__ short Ts[3][RT * TSTR];

    const float c0 = coeffs[0], c1 = coeffs[1], c2 = coeffs[2];
    const float c3 = coeffs[3], c4 = coeffs[4], c5 = coeffs[5];
    const int r0 = blockIdx.x * RT;
    const int tid = threadIdx.x;
    const short* hB = (const short*)h4;

    // phase A: compute h1 rows for this tile directly into Ts[2] (bf16), unroll-8
    // one 16-lane group per node (32 groups = 32 rows)
    {
        int grp = tid >> 4;              // 0..31
        int gl  = tid & 15;
        int node = r0 + grp;
        uint4 o = {0u, 0u, 0u, 0u};
        if (node < N_NODES) {
            int beg = rowstart[node] + bsums[node >> CHUNK_SHIFT];
            int end = (node == N_NODES - 1)
                          ? N_EDGES
                          : rowstart[node + 1] + bsums[(node + 1) >> CHUNK_SHIFT];
            float nv = norm[node];
            float4v a0 = {0.f, 0.f, 0.f, 0.f};
            float4v a1 = {0.f, 0.f, 0.f, 0.f};
            int t = beg;
            for (; t + 7 < end; t += 8) {
                EdgeRec e0 = ldnt2(er + t),     e1 = ldnt2(er + t + 1);
                EdgeRec e2 = ldnt2(er + t + 2), e3 = ldnt2(er + t + 3);
                EdgeRec e4 = ldnt2(er + t + 4), e5 = ldnt2(er + t + 5);
                EdgeRec e6 = ldnt2(er + t + 6), e7 = ldnt2(er + t + 7);
                uint4 r0v = h4[e0.x * 16u + gl];
                uint4 r1v = h4[e1.x * 16u + gl];
                uint4 r2v = h4[e2.x * 16u + gl];
                uint4 r3v = h4[e3.x * 16u + gl];
                uint4 r4v = h4[e4.x * 16u + gl];
                uint4 r5v = h4[e5.x * 16u + gl];
                uint4 r6v = h4[e6.x * 16u + gl];
                uint4 r7v = h4[e7.x * 16u + gl];
                acc8(a0, a1, r0v, __builtin_bit_cast(float, e0.y));
                acc8(a0, a1, r1v, __builtin_bit_cast(float, e1.y));
                acc8(a0, a1, r2v, __builtin_bit_cast(float, e2.y));
                acc8(a0, a1, r3v, __builtin_bit_cast(float, e3.y));
                acc8(a0, a1, r4v, __builtin_bit_cast(float, e4.y));
                acc8(a0, a1, r5v, __builtin_bit_cast(float, e5.y));
                acc8(a0, a1, r6v, __builtin_bit_cast(float, e6.y));
                acc8(a0, a1, r7v, __builtin_bit_cast(float, e7.y));
            }
            if (t + 3 < end) {
                EdgeRec e0 = ldnt2(er + t),     e1 = ldnt2(er + t + 1);
                EdgeRec e2 = ldnt2(er + t + 2), e3 = ldnt2(er + t + 3);
                uint4 r0v = h4[e0.x * 16u + gl];
                uint4 r1v = h4[e1.x * 16u + gl];
                uint4 r2v = h4[e2.x * 16u + gl];
                uint4 r3v = h4[e3.x * 16u + gl];
                acc8(a0, a1, r0v, __builtin_bit_cast(float, e0.y));
                acc8(a0, a1, r1v, __builtin_bit_cast(float, e1.y));
                acc8(a0, a1, r2v, __builtin_bit_cast(float, e2.y));
                acc8(a0, a1, r3v, __builtin_bit_cast(float, e3.y));
                t += 4;
            }
            for (; t < end; ++t) {
                EdgeRec e = ldnt2(er + t);
                uint4 r = h4[e.x * 16u + gl];
                acc8(a0, a1, r, __builtin_bit_cast(float, e.y));
            }
            o.x = pack2(a0.x * nv, a0.y * nv); o.y = pack2(a0.z * nv, a0.w * nv);
            o.z = pack2(a1.x * nv, a1.y * nv); o.w = pack2(a1.z * nv, a1.w * nv);
        }
        *(uint4*)&Ts[2][grp * TSTR + gl * 8] = o;      // 272B row stride -> 16B aligned
    }
    __syncthreads();

    // phase B: blend bf16 h/f (global) + h1 (LDS) -> bf16 T0,T1,T2 tiles
    // 512 threads cover 32 rows x 16 col-groups exactly; same-thread same-addr
    // read->write on Ts[2] -> no extra sync needed.
    {
        int r = tid >> 4;
        int cg = (tid & 15) * 8;
        int row = r0 + r;
        int la = r * TSTR + cg;
        short8 hv = {0,0,0,0,0,0,0,0}, fv = {0,0,0,0,0,0,0,0};
        if (row < N_NODES) {
            size_t base = (size_t)row * DIM + cg;
            hv = *(const short8*)(hB + base);
            fv = *(const short8*)(fB + base);
        }
        short8 h1v = *(const short8*)&Ts[2][la];
        short8 t0, t1, t2;
#pragma unroll
        for (int j = 0; j < 8; ++j) {
            float hf = bf2f(hv[j]), ff = bf2f(fv[j]), h1f = bf2f(h1v[j]);
            t0[j] = f2bf(c0 * hf + c1 * ff);
            t1[j] = f2bf(c2 * hf + c3 * ff);
            t2[j] = f2bf(c4 * h1f + c5 * ff);
        }
        *(short8*)&Ts[0][la] = t0;
        *(short8*)&Ts[1][la] = t1;
        *(short8*)&Ts[2][la] = t2;
    }
    __syncthreads();

    const int lane = tid & 63;
    const int ct = tid >> 6;        // wave owns one 16-col tile
    const int m = lane & 15;
    const int quad = lane >> 4;

    float4v acc[3][2];
    const float4v zero = {0.f, 0.f, 0.f, 0.f};
#pragma unroll
    for (int g = 0; g < 3; ++g)
#pragma unroll
        for (int rt = 0; rt < 2; ++rt) acc[g][rt] = zero;

    const short* wbase = Wb + (ct * 16 + m) * DIM + quad * 8;
#pragma unroll
    for (int ks = 0; ks < 4; ++ks) {
        const short* wp = wbase + ks * 32;
        short8 b0 = *(const short8*)(wp);
        short8 b1 = *(const short8*)(wp + DIM * DIM);
        short8 b2 = *(const short8*)(wp + 2 * DIM * DIM);
#pragma unroll
        for (int rt = 0; rt < 2; ++rt) {
            int aoff = (rt * 16 + m) * TSTR + ks * 32 + quad * 8;
            short8 a0 = *(const short8*)&Ts[0][aoff];
            short8 a1 = *(const short8*)&Ts[1][aoff];
            short8 a2 = *(const short8*)&Ts[2][aoff];
            acc[0][rt] = __builtin_amdgcn_mfma_f32_16x16x32_bf16(a0, b0, acc[0][rt], 0, 0, 0);
            acc[1][rt] = __builtin_amdgcn_mfma_f32_16x16x32_bf16(a1, b1, acc[1][rt], 0, 0, 0);
            acc[2][rt] = __builtin_amdgcn_mfma_f32_16x16x32_bf16(a2, b2, acc[2][rt], 0, 0, 0);
        }
    }

    // epilogue: sequential mutual gating + bias + graph-norm + relu
    const int col = ct * 16 + m;
    const float bc = bias[col];
#pragma unroll
    for (int rt = 0; rt < 2; ++rt) {
#pragma unroll
        for (int r = 0; r < 4; ++r) {
            int row = r0 + rt * 16 + quad * 4 + r;
            if (row < N_NODES) {
                float sn = snorm[row];
                float o0 = acc[0][rt][r], o1 = acc[1][rt][r], o2 = acc[2][rt][r];
                float g0 = o0 * sigm(o1 + o2);
                float g1 = o1 * sigm(g0 + o2);
                float g2 = o2 * sigm(g0 + g1);
                float vv = (g0 + g1 + g2 + bc) * sn;
                __builtin_nontemporal_store(fmaxf(vv, 0.f), &out[(size_t)row * DIM + col]);
            }
        }
    }
}

extern "C" void kernel_launch(void* const* d_in, const int* in_sizes, int n_in,
                              void* d_out, int out_size, void* d_ws, size_t ws_size,
                              hipStream_t stream) {
    const float* feature = (const float*)d_in[0];
    const float* snorm   = (const float*)d_in[1];
    const int*   src     = (const int*)d_in[2];
    const int*   dst     = (const int*)d_in[3];
    const float* W_low   = (const float*)d_in[4];
    const float* W_high  = (const float*)d_in[5];
    const float* W_mid   = (const float*)d_in[6];
    const float* gl      = (const float*)d_in[7];
    const float* gh      = (const float*)d_in[8];
    const float* gm      = (const float*)d_in[9];
    const float* bias    = (const float*)d_in[10];
    float* out = (float*)d_out;

    char* w = (char*)d_ws;
    auto alloc = [&](size_t bytes) {
        char* p = w;
        w += (bytes + 255) & ~(size_t)255;
        return p;
    };
    // deg, cnt, done contiguous -> single memset zeroes all three
    int* deg      = (int*)alloc((size_t)N_NODES * 4);
    int* cnt      = (int*)alloc((size_t)N_NODES * 4);
    int* done     = (int*)alloc(256);
    size_t zero_bytes = (size_t)((char*)done - (char*)deg) + 256;
    float* norm   = (float*)alloc((size_t)N_NODES * 4);
    int* rowstart = (int*)alloc((size_t)(N_NODES + 1) * 4);
    int* bsums    = (int*)alloc(64 * 4);
    uint2* er     = (uint2*)alloc((size_t)N_EDGES * 8);
    float* coeffs = (float*)alloc(64 * 4);
    short* Wb     = (short*)alloc((size_t)3 * DIM * DIM * 2);
    short* fb     = (short*)alloc((size_t)N_NODES * DIM * 2);
    short* h      = (short*)alloc((size_t)N_NODES * DIM * 2);

    // 0: zero deg + cnt + done
    hipMemsetAsync(deg, 0, zero_bytes, stream);
    // 1: fb/Wb/coeffs convert CONCURRENT with degree atomics (disjoint block roles)
    k_prep_deg<<<3174 + 2344, 256, 0, stream>>>(
        (const float4*)feature, W_low, W_high, W_mid, gl, gh, gm, dst,
        (uint4*)fb, (unsigned int*)Wb, coeffs, deg);
    // 2: chunk scan + norm; last block scans chunk sums
    k_scan<<<NCHUNKS, 512, 0, stream>>>(deg, rowstart, bsums, norm, done);
    // 3: CSR fill with packed (src, norm[src]) records
    k_fill<<<(N_EDGES + 255) / 256, 256, 0, stream>>>(src, dst, rowstart, bsums,
                                                      cnt, norm, er);
    // 4: SpMM hop 1 (fb -> h)
    k_spmm<<<(N_NODES + 15) / 16, 256, 0, stream>>>((const uint4*)fb, norm, rowstart,
                                                    bsums, er, (uint4*)h);
    // 5: fused SpMM hop 2 + tri-GEMM + gating (h1 never materialized)
    k_gemm_fused<<<(N_NODES + RT - 1) / RT, 512, 0, stream>>>(
        (const uint4*)h, fb, Wb, rowstart, bsums, norm, er,
        coeffs, bias, snorm, out);
}

// Round 10
// 238.170 us; speedup vs baseline: 1.1694x; 1.0560x over previous
//
#include <hip/hip_runtime.h>
#include <hip/hip_bf16.h>
#include <math.h>

#define N_NODES 50000
#define N_EDGES 600000
#define DIM 128
#define KGAM 8
#define EPSV 1e-9f

// CSR chunk scan: 25 chunks of 2048 nodes
#define CHUNK_SHIFT 11
#define NCHUNKS 25

// k_prep_deg block-role layout: deg atomics FIRST (critical path), then fb, Wb, coeffs
#define DEG_BLKS 2344
#define FB_BLKS  3125
#define WB_BASE  (DEG_BLKS + FB_BLKS)          // 5469
#define CO_BLK   (WB_BASE + 48)                // 5517

typedef __attribute__((ext_vector_type(8))) short short8;
typedef __attribute__((ext_vector_type(4))) float float4v;

__device__ __forceinline__ float bf2f(short s) {
    unsigned int u = ((unsigned int)(unsigned short)s) << 16;
    return __builtin_bit_cast(float, u);
}
__device__ __forceinline__ short f2bf(float f) {
    return (short)__builtin_bit_cast(unsigned short, __float2bfloat16(f));
}
__device__ __forceinline__ unsigned int pack2(float a, float b) {
    return (unsigned int)(unsigned short)f2bf(a) | ((unsigned int)(unsigned short)f2bf(b) << 16);
}
__device__ __forceinline__ float sigm(float x) { return 1.f / (1.f + __expf(-x)); }
__device__ __forceinline__ float ulo(unsigned int u) { return __builtin_bit_cast(float, u << 16); }
__device__ __forceinline__ float uhi(unsigned int u) { return __builtin_bit_cast(float, u & 0xffff0000u); }

__device__ __forceinline__ void acc8(float4v& a0, float4v& a1, uint4 r, float nu) {
    a0.x = fmaf(nu, ulo(r.x), a0.x); a0.y = fmaf(nu, uhi(r.x), a0.y);
    a0.z = fmaf(nu, ulo(r.y), a0.z); a0.w = fmaf(nu, uhi(r.y), a0.w);
    a1.x = fmaf(nu, ulo(r.z), a1.x); a1.y = fmaf(nu, uhi(r.z), a1.y);
    a1.z = fmaf(nu, ulo(r.w), a1.z); a1.w = fmaf(nu, uhi(r.w), a1.w);
}

// ---------------- fused prep: deg atomics (blocks 0..2343, FIRST = critical path)
//                  + fb convert + Wb convert + coeffs (later blocks) ---------------
// deg pre-zeroed by hipMemsetAsync before this kernel.
__global__ void k_prep_deg(const float4* __restrict__ feat4,
                           const float* __restrict__ W0, const float* __restrict__ W1,
                           const float* __restrict__ W2,
                           const float* __restrict__ gl, const float* __restrict__ gh,
                           const float* __restrict__ gm,
                           const int* __restrict__ dst,
                           uint4* __restrict__ fb4, unsigned int* __restrict__ Wb,
                           float* __restrict__ coeffs, int* __restrict__ deg) {
    int b = blockIdx.x, tid = threadIdx.x;
    if (b < DEG_BLKS) {
        int e = b * 256 + tid;
        if (e < N_EDGES) atomicAdd(&deg[dst[e]], 1);
    } else if (b < WB_BASE) {
        int idx = (b - DEG_BLKS) * 256 + tid;        // group of 8 floats; 800000 exact
        float4 v0 = feat4[idx * 2];
        float4 v1 = feat4[idx * 2 + 1];
        uint4 o;
        o.x = pack2(v0.x, v0.y); o.y = pack2(v0.z, v0.w);
        o.z = pack2(v1.x, v1.y); o.w = pack2(v1.z, v1.w);
        fb4[idx] = o;
    } else if (b < CO_BLK) {
        int j = (b - WB_BASE) * 256 + tid;           // [0, 12288)
        int g = j >> 12;
        int i = (j & 4095) * 4;
        const float* Ws = (g == 0) ? W0 : (g == 1) ? W1 : W2;
        float4 v = *(const float4*)(Ws + i);
        uint2 o; o.x = pack2(v.x, v.y); o.y = pack2(v.z, v.w);
        *(uint2*)(Wb + (g * DIM * DIM + i) / 2) = o;
    } else {
        if (tid == 0) {
            float a0 = 0, b0 = 0, a1 = 0, b1 = 0, sg = 0, m2 = 0;
            for (int k = 0; k < KGAM; ++k) {
                float al = EPSV + (float)k * (1.f - 2.f * EPSV) / (KGAM - 1);
                float md = EPSV + (float)k * (1.f - EPSV) / (KGAM - 1);
                float l = fmaxf(gl[k], 0.f), h = fmaxf(gh[k], 0.f), m = fmaxf(gm[k], 0.f);
                a0 += al * l;  b0 += (1.f - al) * l;
                a1 += -al * h; b1 += (1.f - al) * h;
                sg += m;       m2 += md * m;
            }
            coeffs[0] = a0; coeffs[1] = b0; coeffs[2] = a1;
            coeffs[3] = b1; coeffs[4] = sg; coeffs[5] = -m2;
        }
    }
}

// ---------------- fused scan: per-chunk exclusive scan + norm; last block scans
//                  the 25 chunk sums (atomic-ticket pattern, no spin) -------------
__global__ __launch_bounds__(512) void k_scan(const int* __restrict__ deg,
                                              int* __restrict__ rowstart,
                                              int* __restrict__ bsums,
                                              float* __restrict__ norm,
                                              int* __restrict__ done) {
    __shared__ int s[512];
    __shared__ int lastf;
    __shared__ int bs[NCHUNKS];
    int tid = threadIdx.x;
    int i0 = blockIdx.x * 2048 + tid * 4;
    int v[4]; int sum = 0;
#pragma unroll
    for (int c = 0; c < 4; ++c) {
        int i = i0 + c;
        int d = (i < N_NODES) ? deg[i] : 0;
        v[c] = d; sum += d;
    }
    s[tid] = sum; __syncthreads();
#pragma unroll
    for (int off = 1; off < 512; off <<= 1) {
        int t = (tid >= off) ? s[tid - off] : 0;
        __syncthreads();
        s[tid] += t;
        __syncthreads();
    }
    if (tid == 511) bsums[blockIdx.x] = s[511];
    int run = s[tid] - sum;
#pragma unroll
    for (int c = 0; c < 4; ++c) {
        int i = i0 + c;
        if (i < N_NODES) {
            rowstart[i] = run;                       // chunk-local exclusive prefix
            norm[i] = rsqrtf((float)(v[c] < 1 ? 1 : v[c]));
        }
        run += v[c];
    }
    // last-arriving block turns bsums into an exclusive prefix of chunk sums
    __threadfence();
    __syncthreads();
    if (tid == 0) {
        int old = atomicAdd(done, 1);
        lastf = (old == (int)gridDim.x - 1) ? 1 : 0;
    }
    __syncthreads();
    if (lastf) {
        __threadfence();
        if (tid < NCHUNKS) bs[tid] = bsums[tid];
        __syncthreads();
        if (tid == 0) {
            int run2 = 0;
            for (int i = 0; i < NCHUNKS; ++i) { int t = bs[i]; bs[i] = run2; run2 += t; }
        }
        __syncthreads();
        if (tid < NCHUNKS) bsums[tid] = bs[tid];
    }
}

// ---------------- CSR fill: packed (src, norm[src]) records ----------------
__global__ void k_fill(const int* __restrict__ src, const int* __restrict__ dst,
                       const int* __restrict__ rowstart, const int* __restrict__ bsums,
                       int* __restrict__ cnt, const float* __restrict__ norm,
                       uint2* __restrict__ er) {
    int e = blockIdx.x * blockDim.x + threadIdx.x;
    if (e < N_EDGES) {
        int d = dst[e];
        int slot = rowstart[d] + bsums[d >> CHUNK_SHIFT] + atomicAdd(&cnt[d], 1);
        int u = src[e];
        uint2 rec;
        rec.x = (unsigned int)u;
        rec.y = __builtin_bit_cast(unsigned int, norm[u]);
        er[slot] = rec;
    }
}

// ---------------- SpMM hop 1: 16 lanes/node, unroll-8 -----------------------------
// out[v] = bf16(norm[v] * sum_u norm[u]*in[u])
__global__ __launch_bounds__(256, 6) void k_spmm(
    const uint4* __restrict__ in, const float* __restrict__ norm,
    const int* __restrict__ rowstart, const int* __restrict__ bsums,
    const uint2* __restrict__ er, uint4* __restrict__ out) {
    int node = blockIdx.x * 16 + (threadIdx.x >> 4);
    if (node >= N_NODES) return;
    int gl = threadIdx.x & 15;
    int beg = rowstart[node] + bsums[node >> CHUNK_SHIFT];
    int end = (node == N_NODES - 1)
                  ? N_EDGES
                  : rowstart[node + 1] + bsums[(node + 1) >> CHUNK_SHIFT];
    float4v a0 = {0.f, 0.f, 0.f, 0.f};
    float4v a1 = {0.f, 0.f, 0.f, 0.f};
    int t = beg;
    for (; t + 7 < end; t += 8) {
        uint2 e0 = er[t],     e1 = er[t + 1], e2 = er[t + 2], e3 = er[t + 3];
        uint2 e4 = er[t + 4], e5 = er[t + 5], e6 = er[t + 6], e7 = er[t + 7];
        uint4 r0 = in[e0.x * 16u + gl];
        uint4 r1 = in[e1.x * 16u + gl];
        uint4 r2 = in[e2.x * 16u + gl];
        uint4 r3 = in[e3.x * 16u + gl];
        uint4 r4 = in[e4.x * 16u + gl];
        uint4 r5 = in[e5.x * 16u + gl];
        uint4 r6 = in[e6.x * 16u + gl];
        uint4 r7 = in[e7.x * 16u + gl];
        acc8(a0, a1, r0, __builtin_bit_cast(float, e0.y));
        acc8(a0, a1, r1, __builtin_bit_cast(float, e1.y));
        acc8(a0, a1, r2, __builtin_bit_cast(float, e2.y));
        acc8(a0, a1, r3, __builtin_bit_cast(float, e3.y));
        acc8(a0, a1, r4, __builtin_bit_cast(float, e4.y));
        acc8(a0, a1, r5, __builtin_bit_cast(float, e5.y));
        acc8(a0, a1, r6, __builtin_bit_cast(float, e6.y));
        acc8(a0, a1, r7, __builtin_bit_cast(float, e7.y));
    }
    if (t + 3 < end) {
        uint2 e0 = er[t], e1 = er[t + 1], e2 = er[t + 2], e3 = er[t + 3];
        uint4 r0 = in[e0.x * 16u + gl];
        uint4 r1 = in[e1.x * 16u + gl];
        uint4 r2 = in[e2.x * 16u + gl];
        uint4 r3 = in[e3.x * 16u + gl];
        acc8(a0, a1, r0, __builtin_bit_cast(float, e0.y));
        acc8(a0, a1, r1, __builtin_bit_cast(float, e1.y));
        acc8(a0, a1, r2, __builtin_bit_cast(float, e2.y));
        acc8(a0, a1, r3, __builtin_bit_cast(float, e3.y));
        t += 4;
    }
    for (; t < end; ++t) {
        uint2 e = er[t];
        uint4 r = in[e.x * 16u + gl];
        acc8(a0, a1, r, __builtin_bit_cast(float, e.y));
    }
    float nv = norm[node];
    uint4 o;
    o.x = pack2(a0.x * nv, a0.y * nv); o.y = pack2(a0.z * nv, a0.w * nv);
    o.z = pack2(a1.x * nv, a1.y * nv); o.w = pack2(a1.z * nv, a1.w * nv);
    out[node * 16u + gl] = o;
}

// ---------------- fused: SpMM hop 2 (h -> h1, LDS-resident) + tri-GEMM + gating ---
// A: lane holds A[m=lane&15][k=quad*8+j]; B: lane holds W[n=lane&15][k=quad*8+j];
// C/D: col=lane&15, row=quad*4+reg  (verified layout)
// RT=32: LDS 26112B -> ~46% occupancy measured (R6).
#define RT 32
#define TSTR 136

__global__ __launch_bounds__(512, 4) void k_gemm_fused(
    const uint4* __restrict__ h4, const short* __restrict__ fB,
    const short* __restrict__ Wb,
    const int* __restrict__ rowstart, const int* __restrict__ bsums,
    const float* __restrict__ norm, const uint2* __restrict__ er,
    const float* __restrict__ coeffs, const float* __restrict__ bias,
    const float* __restrict__ snorm, float* __restrict__ out) {
    __shared__ short Ts[3][RT * TSTR];

    const float c0 = coeffs[0], c1 = coeffs[1], c2 = coeffs[2];
    const float c3 = coeffs[3], c4 = coeffs[4], c5 = coeffs[5];
    const int r0 = blockIdx.x * RT;
    const int tid = threadIdx.x;
    const short* hB = (const short*)h4;

    // phase A: compute h1 rows for this tile directly into Ts[2] (bf16), unroll-8
    // one 16-lane group per node (32 groups = 32 rows)
    {
        int grp = tid >> 4;              // 0..31
        int gl  = tid & 15;
        int node = r0 + grp;
        uint4 o = {0u, 0u, 0u, 0u};
        if (node < N_NODES) {
            int beg = rowstart[node] + bsums[node >> CHUNK_SHIFT];
            int end = (node == N_NODES - 1)
                          ? N_EDGES
                          : rowstart[node + 1] + bsums[(node + 1) >> CHUNK_SHIFT];
            float nv = norm[node];
            float4v a0 = {0.f, 0.f, 0.f, 0.f};
            float4v a1 = {0.f, 0.f, 0.f, 0.f};
            int t = beg;
            for (; t + 7 < end; t += 8) {
                uint2 e0 = er[t],     e1 = er[t + 1], e2 = er[t + 2], e3 = er[t + 3];
                uint2 e4 = er[t + 4], e5 = er[t + 5], e6 = er[t + 6], e7 = er[t + 7];
                uint4 r0v = h4[e0.x * 16u + gl];
                uint4 r1v = h4[e1.x * 16u + gl];
                uint4 r2v = h4[e2.x * 16u + gl];
                uint4 r3v = h4[e3.x * 16u + gl];
                uint4 r4v = h4[e4.x * 16u + gl];
                uint4 r5v = h4[e5.x * 16u + gl];
                uint4 r6v = h4[e6.x * 16u + gl];
                uint4 r7v = h4[e7.x * 16u + gl];
                acc8(a0, a1, r0v, __builtin_bit_cast(float, e0.y));
                acc8(a0, a1, r1v, __builtin_bit_cast(float, e1.y));
                acc8(a0, a1, r2v, __builtin_bit_cast(float, e2.y));
                acc8(a0, a1, r3v, __builtin_bit_cast(float, e3.y));
                acc8(a0, a1, r4v, __builtin_bit_cast(float, e4.y));
                acc8(a0, a1, r5v, __builtin_bit_cast(float, e5.y));
                acc8(a0, a1, r6v, __builtin_bit_cast(float, e6.y));
                acc8(a0, a1, r7v, __builtin_bit_cast(float, e7.y));
            }
            if (t + 3 < end) {
                uint2 e0 = er[t], e1 = er[t + 1], e2 = er[t + 2], e3 = er[t + 3];
                uint4 r0v = h4[e0.x * 16u + gl];
                uint4 r1v = h4[e1.x * 16u + gl];
                uint4 r2v = h4[e2.x * 16u + gl];
                uint4 r3v = h4[e3.x * 16u + gl];
                acc8(a0, a1, r0v, __builtin_bit_cast(float, e0.y));
                acc8(a0, a1, r1v, __builtin_bit_cast(float, e1.y));
                acc8(a0, a1, r2v, __builtin_bit_cast(float, e2.y));
                acc8(a0, a1, r3v, __builtin_bit_cast(float, e3.y));
                t += 4;
            }
            for (; t < end; ++t) {
                uint2 e = er[t];
                uint4 r = h4[e.x * 16u + gl];
                acc8(a0, a1, r, __builtin_bit_cast(float, e.y));
            }
            o.x = pack2(a0.x * nv, a0.y * nv); o.y = pack2(a0.z * nv, a0.w * nv);
            o.z = pack2(a1.x * nv, a1.y * nv); o.w = pack2(a1.z * nv, a1.w * nv);
        }
        *(uint4*)&Ts[2][grp * TSTR + gl * 8] = o;      // 272B row stride -> 16B aligned
    }
    __syncthreads();

    // phase B: blend bf16 h/f (global) + h1 (LDS) -> bf16 T0,T1,T2 tiles
    // 512 threads cover 32 rows x 16 col-groups exactly; same-thread same-addr
    // read->write on Ts[2] -> no extra sync needed.
    {
        int r = tid >> 4;
        int cg = (tid & 15) * 8;
        int row = r0 + r;
        int la = r * TSTR + cg;
        short8 hv = {0,0,0,0,0,0,0,0}, fv = {0,0,0,0,0,0,0,0};
        if (row < N_NODES) {
            size_t base = (size_t)row * DIM + cg;
            hv = *(const short8*)(hB + base);
            fv = *(const short8*)(fB + base);
        }
        short8 h1v = *(const short8*)&Ts[2][la];
        short8 t0, t1, t2;
#pragma unroll
        for (int j = 0; j < 8; ++j) {
            float hf = bf2f(hv[j]), ff = bf2f(fv[j]), h1f = bf2f(h1v[j]);
            t0[j] = f2bf(c0 * hf + c1 * ff);
            t1[j] = f2bf(c2 * hf + c3 * ff);
            t2[j] = f2bf(c4 * h1f + c5 * ff);
        }
        *(short8*)&Ts[0][la] = t0;
        *(short8*)&Ts[1][la] = t1;
        *(short8*)&Ts[2][la] = t2;
    }
    __syncthreads();

    const int lane = tid & 63;
    const int ct = tid >> 6;        // wave owns one 16-col tile
    const int m = lane & 15;
    const int quad = lane >> 4;

    float4v acc[3][2];
    const float4v zero = {0.f, 0.f, 0.f, 0.f};
#pragma unroll
    for (int g = 0; g < 3; ++g)
#pragma unroll
        for (int rt = 0; rt < 2; ++rt) acc[g][rt] = zero;

    const short* wbase = Wb + (ct * 16 + m) * DIM + quad * 8;
#pragma unroll
    for (int ks = 0; ks < 4; ++ks) {
        const short* wp = wbase + ks * 32;
        short8 b0 = *(const short8*)(wp);
        short8 b1 = *(const short8*)(wp + DIM * DIM);
        short8 b2 = *(const short8*)(wp + 2 * DIM * DIM);
#pragma unroll
        for (int rt = 0; rt < 2; ++rt) {
            int aoff = (rt * 16 + m) * TSTR + ks * 32 + quad * 8;
            short8 a0 = *(const short8*)&Ts[0][aoff];
            short8 a1 = *(const short8*)&Ts[1][aoff];
            short8 a2 = *(const short8*)&Ts[2][aoff];
            acc[0][rt] = __builtin_amdgcn_mfma_f32_16x16x32_bf16(a0, b0, acc[0][rt], 0, 0, 0);
            acc[1][rt] = __builtin_amdgcn_mfma_f32_16x16x32_bf16(a1, b1, acc[1][rt], 0, 0, 0);
            acc[2][rt] = __builtin_amdgcn_mfma_f32_16x16x32_bf16(a2, b2, acc[2][rt], 0, 0, 0);
        }
    }

    // epilogue: sequential mutual gating + bias + graph-norm + relu
    const int col = ct * 16 + m;
    const float bc = bias[col];
#pragma unroll
    for (int rt = 0; rt < 2; ++rt) {
#pragma unroll
        for (int r = 0; r < 4; ++r) {
            int row = r0 + rt * 16 + quad * 4 + r;
            if (row < N_NODES) {
                float sn = snorm[row];
                float o0 = acc[0][rt][r], o1 = acc[1][rt][r], o2 = acc[2][rt][r];
                float g0 = o0 * sigm(o1 + o2);
                float g1 = o1 * sigm(g0 + o2);
                float g2 = o2 * sigm(g0 + g1);
                float vv = (g0 + g1 + g2 + bc) * sn;
                __builtin_nontemporal_store(fmaxf(vv, 0.f), &out[(size_t)row * DIM + col]);
            }
        }
    }
}

extern "C" void kernel_launch(void* const* d_in, const int* in_sizes, int n_in,
                              void* d_out, int out_size, void* d_ws, size_t ws_size,
                              hipStream_t stream) {
    const float* feature = (const float*)d_in[0];
    const float* snorm   = (const float*)d_in[1];
    const int*   src     = (const int*)d_in[2];
    const int*   dst     = (const int*)d_in[3];
    const float* W_low   = (const float*)d_in[4];
    const float* W_high  = (const float*)d_in[5];
    const float* W_mid   = (const float*)d_in[6];
    const float* gl      = (const float*)d_in[7];
    const float* gh      = (const float*)d_in[8];
    const float* gm      = (const float*)d_in[9];
    const float* bias    = (const float*)d_in[10];
    float* out = (float*)d_out;

    char* w = (char*)d_ws;
    auto alloc = [&](size_t bytes) {
        char* p = w;
        w += (bytes + 255) & ~(size_t)255;
        return p;
    };
    // deg, cnt, done contiguous -> single memset zeroes all three
    int* deg      = (int*)alloc((size_t)N_NODES * 4);
    int* cnt      = (int*)alloc((size_t)N_NODES * 4);
    int* done     = (int*)alloc(256);
    size_t zero_bytes = (size_t)((char*)done - (char*)deg) + 256;
    float* norm   = (float*)alloc((size_t)N_NODES * 4);
    int* rowstart = (int*)alloc((size_t)(N_NODES + 1) * 4);
    int* bsums    = (int*)alloc(64 * 4);
    uint2* er     = (uint2*)alloc((size_t)N_EDGES * 8);
    float* coeffs = (float*)alloc(64 * 4);
    short* Wb     = (short*)alloc((size_t)3 * DIM * DIM * 2);
    short* fb     = (short*)alloc((size_t)N_NODES * DIM * 2);
    short* h      = (short*)alloc((size_t)N_NODES * DIM * 2);

    // 0: zero deg + cnt + done
    hipMemsetAsync(deg, 0, zero_bytes, stream);
    // 1: deg atomics first (critical path), fb/Wb/coeffs overlap behind them
    k_prep_deg<<<CO_BLK + 1, 256, 0, stream>>>(
        (const float4*)feature, W_low, W_high, W_mid, gl, gh, gm, dst,
        (uint4*)fb, (unsigned int*)Wb, coeffs, deg);
    // 2: chunk scan + norm; last block scans chunk sums
    k_scan<<<NCHUNKS, 512, 0, stream>>>(deg, rowstart, bsums, norm, done);
    // 3: CSR fill with packed (src, norm[src]) records
    k_fill<<<(N_EDGES + 255) / 256, 256, 0, stream>>>(src, dst, rowstart, bsums,
                                                      cnt, norm, er);
    // 4: SpMM hop 1 (fb -> h)
    k_spmm<<<(N_NODES + 15) / 16, 256, 0, stream>>>((const uint4*)fb, norm, rowstart,
                                                    bsums, er, (uint4*)h);
    // 5: fused SpMM hop 2 + tri-GEMM + gating (h1 never materialized)
    k_gemm_fused<<<(N_NODES + RT - 1) / RT, 512, 0, stream>>>(
        (const uint4*)h, fb, Wb, rowstart, bsums, norm, er,
        coeffs, bias, snorm, out);
}